// Round 2
// baseline (5141.814 us; speedup 1.0000x reference)
//
#include <hip/hip_runtime.h>

// MPS forward, MI355X/gfx950.
// B=4096 S=256 F=32 D=64 O=16, LABEL=128.
// Strategy: per-site GEMM v' = (v (x) x) @ W  with K=(d,f)=2048, N=64 using
// mfma_f32_32x32x16_f16. A-operand synthesized in registers (outer product,
// v_pk_mul_f16), B-operand (W) pre-swizzled to MFMA fragment order in ws
// (fp16) so the K-loop reads it via coalesced 16B global loads (L2-multicast
// across blocks).
// Chain kernel: 128 blocks (64 left-chain, 64 right-chain), 64 batch rows
// each, 4 waves K-split 4-way, LDS float atomics into ping-pong fp32 state.
// Label kernel: same structure, N=(e,o)=1024, r-contraction fused in regs.

typedef _Float16 half2v __attribute__((ext_vector_type(2)));
typedef _Float16 half8 __attribute__((ext_vector_type(8)));
typedef float f32x16 __attribute__((ext_vector_type(16)));
typedef unsigned int uint4v __attribute__((ext_vector_type(4)));

#define MFMA32(a, b, c) __builtin_amdgcn_mfma_f32_32x32x16_f16((a), (b), (c), 0, 0, 0)

#define VPAD 66  // fp32 state row stride (64 + 2 pad: bank spread, b64-aligned)

// workspace byte offsets (total 72,613,888 bytes required)
#define WS_WLF 0L
#define WS_WRF 33292288L
#define WS_WLAB 66322432L
#define WS_V 70516736L
#define WS_R 71565312L

__device__ __forceinline__ f32x16 zero16() {
  f32x16 z;
#pragma unroll
  for (int i = 0; i < 16; ++i) z[i] = 0.0f;
  return z;
}

__device__ __forceinline__ unsigned int pack2h(float a, float b) {
  half2v h;
  h[0] = (_Float16)a;
  h[1] = (_Float16)b;
  return __builtin_bit_cast(unsigned int, h);
}

__device__ __forceinline__ half2v splat2(float a) {
  _Float16 x = (_Float16)a;
  half2v h;
  h[0] = x;
  h[1] = x;
  return h;
}

// A-fragment synth: splat-scalar * f16-octet (4x v_pk_mul_f16)
__device__ __forceinline__ half8 mulfrag(const half2v s, const unsigned int* o) {
  uint4v t;
#pragma unroll
  for (int i = 0; i < 4; ++i) {
    half2v b = __builtin_bit_cast(half2v, o[i]);
    half2v p = s * b;
    t[i] = __builtin_bit_cast(unsigned int, p);
  }
  return __builtin_bit_cast(half8, t);
}

// ---------------------------------------------------------------------------
// Prologue: convert W to fp16 in MFMA B-fragment order.
// Fragment id F = ((site*128 + s)*2 + t)*64 + lane  (chains)
//             F = (s*32 + t)*64 + lane              (label)
// value j of fragment: B[k = s*16 + (lane>>5)*8 + j][n = t*32 + (lane&31)]
// left/label: k=(d,f) -> d=k>>5, f=k&31 ; n=e (left) or n=(e*16+o) (label)
// right:      k=(f,e) -> f=k>>6, e=k&63 ; n=d
// ---------------------------------------------------------------------------
__global__ void prep_kernel(const float* __restrict__ wl, const float* __restrict__ wr,
                            const float* __restrict__ wlab,
                            _Float16* __restrict__ wlf, _Float16* __restrict__ wrf,
                            _Float16* __restrict__ wlabf) {
  const long t0 = (long)blockIdx.x * blockDim.x + threadIdx.x;
  const long stride = (long)gridDim.x * blockDim.x;
  const long NL = 127L * 128 * 2 * 64;
  const long NR = 126L * 128 * 2 * 64;
  const long NB = 128L * 32 * 64;

  for (long F = t0; F < NL; F += stride) {
    const int l = (int)(F & 63), t = (int)((F >> 6) & 1);
    const int s = (int)((F >> 7) & 127), site = (int)(F >> 14);
    const int k0 = s * 16 + ((l >> 5) << 3);
    const int d = k0 >> 5, f0 = k0 & 31, e = t * 32 + (l & 31);
    const float* src = wl + (((long)site * 64 + d) * 32 + f0) * 64 + e;
    half8 v;
#pragma unroll
    for (int j = 0; j < 8; ++j) v[j] = (_Float16)src[(long)j * 64];
    *(half8*)(wlf + F * 8) = v;
  }
  for (long F = t0; F < NR; F += stride) {
    const int l = (int)(F & 63), t = (int)((F >> 6) & 1);
    const int s = (int)((F >> 7) & 127), site = (int)(F >> 14);
    const int k0 = s * 16 + ((l >> 5) << 3);
    const int f = k0 >> 6, e0 = k0 & 63, d = t * 32 + (l & 31);
    const float* src = wr + (((long)site * 64 + d) * 32 + f) * 64 + e0;
    half8 v;
#pragma unroll
    for (int j = 0; j < 8; ++j) v[j] = (_Float16)src[j];
    *(half8*)(wrf + F * 8) = v;
  }
  for (long F = t0; F < NB; F += stride) {
    const int l = (int)(F & 63), t = (int)((F >> 6) & 31);
    const int s = (int)(F >> 11);
    const int k0 = s * 16 + ((l >> 5) << 3);
    const int d = k0 >> 5, f0 = k0 & 31;
    const int n = t * 32 + (l & 31);
    const int e = n >> 4, oo = n & 15;
    const float* src = wlab + (((long)d * 32 + f0) * 64 + e) * 16 + oo;
    half8 v;
#pragma unroll
    for (int j = 0; j < 8; ++j) v[j] = (_Float16)src[(long)j * 1024];
    *(half8*)(wlabf + F * 8) = v;
  }
}

// ---------------------------------------------------------------------------
// Chain kernel: blocks 0..63 = left chain, 64..127 = right chain; 64 rows each.
// ---------------------------------------------------------------------------
__launch_bounds__(256, 1)
__global__ void chain_kernel(const float* __restrict__ x, const float* __restrict__ w0,
                             const float* __restrict__ wlast,
                             const _Float16* __restrict__ wlf,
                             const _Float16* __restrict__ wrf,
                             float* __restrict__ wsV, float* __restrict__ wsR) {
  __shared__ float vacc[2][64 * VPAD];       // ping-pong fp32 state/accumulator
  __shared__ unsigned int xsf[2][2][64][4];  // left: x octets keyed by [u][parity][lane]
  __shared__ unsigned int xplu[64][17];      // right: packed f16 x scalars [row][f/2]
  __shared__ float xinit[64][33];            // fp32 x for init GEMM

  const int tid = threadIdx.x;
  const int lane = tid & 63;
  const int wv = tid >> 6;  // wave 0..3 = K-quarter
  const int m = lane & 31;  // row-in-tile / col-in-tile
  const int h = lane >> 5;  // half-wave
  const int chain = blockIdx.x >> 6;  // 0 = left(v), 1 = right(r)
  const int b0 = (blockIdx.x & 63) * 64;

  // ---- init state: v0 = x[:,0] @ W0   |   r0[d] = sum_f x[:,255][f]*Wlast[d][f]
  {
    const int row = tid >> 2, c8 = (tid & 3) * 8;
    const float* xp = x + ((long)(b0 + row) * 256 + (chain ? 255 : 0)) * 32 + c8;
    const float4 xa = ((const float4*)xp)[0];
    const float4 xb = ((const float4*)xp)[1];
    xinit[row][c8 + 0] = xa.x; xinit[row][c8 + 1] = xa.y;
    xinit[row][c8 + 2] = xa.z; xinit[row][c8 + 3] = xa.w;
    xinit[row][c8 + 4] = xb.x; xinit[row][c8 + 5] = xb.y;
    xinit[row][c8 + 6] = xb.z; xinit[row][c8 + 7] = xb.w;
  }
  __syncthreads();
  {
    const int row = tid >> 2, c0 = (tid & 3) * 16;
    for (int c = 0; c < 16; ++c) {
      const int col = c0 + c;
      float acc = 0.f;
      if (chain == 0) {
#pragma unroll 8
        for (int f = 0; f < 32; ++f) acc += xinit[row][f] * w0[f * 64 + col];
      } else {
#pragma unroll 8
        for (int f = 0; f < 32; ++f) acc += xinit[row][f] * wlast[col * 32 + f];
      }
      vacc[1][row * VPAD + col] = acc;
    }
  }
  __syncthreads();

  const int NIT = chain ? 126 : 127;

  for (int it = 0; it < NIT; ++it) {
    float* P = vacc[it & 1];                 // this site's accumulator (pre-zeroed below)
    const float* Q = vacc[(it + 1) & 1];     // previous state
    const int site = chain ? (254 - it) : (1 + it);

    // ======== phase A: stage x, zero P, preload state regs
    {
      const int row = tid >> 2, c8 = (tid & 3) * 8;
      const float* xp = x + ((long)(b0 + row) * 256 + site) * 32 + c8;
      const float4 xa = ((const float4*)xp)[0];
      const float4 xb = ((const float4*)xp)[1];
      const unsigned int q0 = pack2h(xa.x, xa.y);
      const unsigned int q1 = pack2h(xa.z, xa.w);
      const unsigned int q2 = pack2h(xb.x, xb.y);
      const unsigned int q3 = pack2h(xb.z, xb.w);
      if (chain == 0) {
        unsigned int* dst = &xsf[row >> 5][c8 >> 4][((c8 >> 3) & 1) * 32 + (row & 31)][0];
        dst[0] = q0; dst[1] = q1; dst[2] = q2; dst[3] = q3;
      } else {
        unsigned int* dst = &xplu[row][c8 >> 1];
        dst[0] = q0; dst[1] = q1; dst[2] = q2; dst[3] = q3;
      }
    }
    for (int i = tid; i < 64 * VPAD; i += 256) P[i] = 0.f;

    half2v vsp[2][16];            // left: splatted v scalars, d in [wv*16, wv*16+16)
    unsigned int roct[2][4][4];   // right: r octets (f16x2 x4) at e0 = 16c + 8h
    if (chain == 0) {
#pragma unroll
      for (int u = 0; u < 2; ++u) {
        const float* src = Q + (u * 32 + m) * VPAD + wv * 16;
#pragma unroll
        for (int qq = 0; qq < 8; ++qq) {
          const float2 f2 = *(const float2*)(src + 2 * qq);
          vsp[u][2 * qq] = splat2(f2.x);
          vsp[u][2 * qq + 1] = splat2(f2.y);
        }
      }
    } else {
#pragma unroll
      for (int u = 0; u < 2; ++u) {
        const float* src = Q + (u * 32 + m) * VPAD + 8 * h;
#pragma unroll
        for (int c = 0; c < 4; ++c)
#pragma unroll
          for (int i = 0; i < 4; ++i) {
            const float2 f2 = *(const float2*)(src + 16 * c + 2 * i);
            roct[u][c][i] = pack2h(f2.x, f2.y);
          }
      }
    }
    __syncthreads();

    // ======== K-loop: wave handles K-quarter, all 4 (t,u) tiles
    f32x16 a00 = zero16(), a01 = zero16(), a10 = zero16(), a11 = zero16();

    if (chain == 0) {
      unsigned int xo[2][2][4];
#pragma unroll
      for (int u = 0; u < 2; ++u)
#pragma unroll
        for (int p = 0; p < 2; ++p)
#pragma unroll
          for (int i = 0; i < 4; ++i) xo[u][p][i] = xsf[u][p][lane][i];

      const _Float16* wb = wlf + (long)it * 131072 + wv * 32768 + lane * 8;
#pragma unroll
      for (int qq = 0; qq < 16; ++qq) {
        const int o0 = (2 * qq) * 1024;
        half8 b00 = *(const half8*)(wb + o0);
        half8 b10 = *(const half8*)(wb + o0 + 512);
        half8 b01 = *(const half8*)(wb + o0 + 1024);
        half8 b11 = *(const half8*)(wb + o0 + 1536);
        half8 ae0 = mulfrag(vsp[0][qq], xo[0][0]);
        half8 ae1 = mulfrag(vsp[1][qq], xo[1][0]);
        a00 = MFMA32(ae0, b00, a00);
        a01 = MFMA32(ae1, b00, a01);
        a10 = MFMA32(ae0, b10, a10);
        a11 = MFMA32(ae1, b10, a11);
        half8 ao0 = mulfrag(vsp[0][qq], xo[0][1]);
        half8 ao1 = mulfrag(vsp[1][qq], xo[1][1]);
        a00 = MFMA32(ao0, b01, a00);
        a01 = MFMA32(ao1, b01, a01);
        a10 = MFMA32(ao0, b11, a10);
        a11 = MFMA32(ao1, b11, a11);
      }
    } else {
      half2v xsp[2][8];  // splatted x scalars, f in [8wv, 8wv+8)
#pragma unroll
      for (int u = 0; u < 2; ++u)
#pragma unroll
        for (int i = 0; i < 8; ++i) {
          const int f = 8 * wv + i;
          const half2v pw = __builtin_bit_cast(half2v, xplu[u * 32 + m][f >> 1]);
          const _Float16 xv = (f & 1) ? pw[1] : pw[0];
          half2v sp; sp[0] = xv; sp[1] = xv;
          xsp[u][i] = sp;
        }
      const _Float16* wb = wrf + (long)(125 - it) * 131072 + wv * 32768 + lane * 8;
#pragma unroll
      for (int qq = 0; qq < 8; ++qq) {
#pragma unroll
        for (int c = 0; c < 4; ++c) {
          const int o0 = (4 * qq + c) * 1024;
          half8 bt0 = *(const half8*)(wb + o0);
          half8 bt1 = *(const half8*)(wb + o0 + 512);
          half8 af0 = mulfrag(xsp[0][qq], roct[0][c]);
          half8 af1 = mulfrag(xsp[1][qq], roct[1][c]);
          a00 = MFMA32(af0, bt0, a00);
          a01 = MFMA32(af1, bt0, a01);
          a10 = MFMA32(af0, bt1, a10);
          a11 = MFMA32(af1, bt1, a11);
        }
      }
    }

    // ======== epilogue: K-reduction across waves via LDS float atomics
    {
      auto addt = [&](const f32x16& a, const int t, const int u) {
#pragma unroll
        for (int g = 0; g < 16; ++g) {
          const int r = (g & 3) + ((g >> 2) << 3) + (h << 2);
          atomicAdd(&P[(u * 32 + r) * VPAD + t * 32 + m], a[g]);
        }
      };
      switch (wv) {  // rotate tile order to avoid same-address atomic pileup
        case 0: addt(a00, 0, 0); addt(a01, 0, 1); addt(a10, 1, 0); addt(a11, 1, 1); break;
        case 1: addt(a01, 0, 1); addt(a10, 1, 0); addt(a11, 1, 1); addt(a00, 0, 0); break;
        case 2: addt(a10, 1, 0); addt(a11, 1, 1); addt(a00, 0, 0); addt(a01, 0, 1); break;
        default: addt(a11, 1, 1); addt(a00, 0, 0); addt(a01, 0, 1); addt(a10, 1, 0); break;
      }
    }
    __syncthreads();
  }

  // ---- store final state to workspace
  {
    const float* FB = vacc[(NIT - 1) & 1];
    float* dst = (chain ? wsR : wsV) + (long)b0 * 64;
    for (int i = tid; i < 4096; i += 256) dst[i] = FB[(i >> 6) * VPAD + (i & 63)];
  }
}

// ---------------------------------------------------------------------------
// Label kernel: logits[b,o] = sum_e r_be * [ (v (x) x_label) @ Wlab ]_{b,(e,o)}
// ---------------------------------------------------------------------------
__launch_bounds__(256, 1)
__global__ void label_kernel(const float* __restrict__ x,
                             const _Float16* __restrict__ wlabf,
                             const float* __restrict__ wsV, const float* __restrict__ wsR,
                             float* __restrict__ out) {
  __shared__ float vsh[64 * VPAD];
  __shared__ float rsh[64 * VPAD];
  __shared__ unsigned int xsf[2][2][64][4];
  __shared__ float lacc[64][17];

  const int tid = threadIdx.x, lane = tid & 63, wv = tid >> 6;
  const int m = lane & 31, h = lane >> 5;
  const int b0 = blockIdx.x * 64;

  for (int i = tid; i < 4096; i += 256) {
    vsh[(i >> 6) * VPAD + (i & 63)] = wsV[(long)b0 * 64 + i];
    rsh[(i >> 6) * VPAD + (i & 63)] = wsR[(long)b0 * 64 + i];
  }
  for (int i = tid; i < 64 * 17; i += 256) ((float*)lacc)[i] = 0.f;
  {
    const int row = tid >> 2, c8 = (tid & 3) * 8;
    const float* xp = x + ((long)(b0 + row) * 256 + 128) * 32 + c8;
    const float4 xa = ((const float4*)xp)[0];
    const float4 xb = ((const float4*)xp)[1];
    unsigned int* dst = &xsf[row >> 5][c8 >> 4][((c8 >> 3) & 1) * 32 + (row & 31)][0];
    dst[0] = pack2h(xa.x, xa.y);
    dst[1] = pack2h(xa.z, xa.w);
    dst[2] = pack2h(xb.x, xb.y);
    dst[3] = pack2h(xb.z, xb.w);
  }
  __syncthreads();

  half2v vsp[2][16];
#pragma unroll
  for (int u = 0; u < 2; ++u) {
    const float* src = vsh + (u * 32 + m) * VPAD + wv * 16;
#pragma unroll
    for (int qq = 0; qq < 8; ++qq) {
      const float2 f2 = *(const float2*)(src + 2 * qq);
      vsp[u][2 * qq] = splat2(f2.x);
      vsp[u][2 * qq + 1] = splat2(f2.y);
    }
  }
  unsigned int xo[2][2][4];
#pragma unroll
  for (int u = 0; u < 2; ++u)
#pragma unroll
    for (int p = 0; p < 2; ++p)
#pragma unroll
      for (int i = 0; i < 4; ++i) xo[u][p][i] = xsf[u][p][lane][i];

  float lg0[16], lg1[16];
#pragma unroll
  for (int g = 0; g < 16; ++g) { lg0[g] = 0.f; lg1[g] = 0.f; }

  const _Float16* wbase = wlabf + (long)wv * 32 * 16384 + lane * 8;
  for (int g2 = 0; g2 < 16; ++g2) {  // n-groups: 2 n-tiles each
    f32x16 a00 = zero16(), a01 = zero16(), a10 = zero16(), a11 = zero16();
    const _Float16* wg = wbase + g2 * 1024;
#pragma unroll
    for (int qq = 0; qq < 16; ++qq) {
      const long o0 = (long)(2 * qq) * 16384;
      half8 b00 = *(const half8*)(wg + o0);
      half8 b10 = *(const half8*)(wg + o0 + 512);
      half8 b01 = *(const half8*)(wg + o0 + 16384);
      half8 b11 = *(const half8*)(wg + o0 + 16384 + 512);
      half8 ae0 = mulfrag(vsp[0][qq], xo[0][0]);
      half8 ae1 = mulfrag(vsp[1][qq], xo[1][0]);
      a00 = MFMA32(ae0, b00, a00);
      a01 = MFMA32(ae1, b00, a01);
      a10 = MFMA32(ae0, b10, a10);
      a11 = MFMA32(ae1, b10, a11);
      half8 ao0 = mulfrag(vsp[0][qq], xo[0][1]);
      half8 ao1 = mulfrag(vsp[1][qq], xo[1][1]);
      a00 = MFMA32(ao0, b01, a00);
      a01 = MFMA32(ao1, b01, a01);
      a10 = MFMA32(ao0, b11, a10);
      a11 = MFMA32(ao1, b11, a11);
    }
    // fold N-tiles into per-lane logit accumulators: n = t*32+m -> e = t*2+(m>>4), o = m&15
    const int e0 = g2 * 4 + (m >> 4);
#pragma unroll
    for (int g = 0; g < 16; ++g) {
      const int r = (g & 3) + ((g >> 2) << 3) + (h << 2);
      lg0[g] += a00[g] * rsh[r * VPAD + e0] + a10[g] * rsh[r * VPAD + e0 + 2];
      lg1[g] += a01[g] * rsh[(32 + r) * VPAD + e0] + a11[g] * rsh[(32 + r) * VPAD + e0 + 2];
    }
  }
#pragma unroll
  for (int g = 0; g < 16; ++g) {
    const int r = (g & 3) + ((g >> 2) << 3) + (h << 2);
    atomicAdd(&lacc[r][m & 15], lg0[g]);
    atomicAdd(&lacc[32 + r][m & 15], lg1[g]);
  }
  __syncthreads();
  for (int i = tid; i < 1024; i += 256) out[(long)b0 * 16 + i] = lacc[i >> 4][i & 15];
}

extern "C" void kernel_launch(void* const* d_in, const int* in_sizes, int n_in,
                              void* d_out, int out_size, void* d_ws, size_t ws_size,
                              hipStream_t stream) {
  const float* x = (const float*)d_in[0];      // (4096,256,32)
  const float* w0 = (const float*)d_in[1];     // (32,64)
  const float* wl = (const float*)d_in[2];     // (127,64,32,64)
  const float* wlab = (const float*)d_in[3];   // (64,32,64,16)
  const float* wr = (const float*)d_in[4];     // (126,64,32,64)
  const float* wlast = (const float*)d_in[5];  // (64,32)

  char* ws = (char*)d_ws;
  _Float16* wlf = (_Float16*)(ws + WS_WLF);
  _Float16* wrf = (_Float16*)(ws + WS_WRF);
  _Float16* wlabf = (_Float16*)(ws + WS_WLAB);
  float* wsV = (float*)(ws + WS_V);
  float* wsR = (float*)(ws + WS_R);

  prep_kernel<<<2048, 256, 0, stream>>>(wl, wr, wlab, wlf, wrf, wlabf);
  chain_kernel<<<128, 256, 0, stream>>>(x, w0, wlast, wlf, wrf, wsV, wsR);
  label_kernel<<<64, 256, 0, stream>>>(x, wlabf, wsV, wsR, (float*)d_out);
}